// Round 10
// baseline (841.674 us; speedup 1.0000x reference)
//
#include <hip/hip_runtime.h>
#include <hip/hip_bf16.h>

#define D_MODEL 1024
#define HEADS 16
#define HSZ 64
#define BATCH 2
#define SEQ 2048
#define TOK (BATCH*SEQ)   // 4096
#define NT2 (SEQ/128)     // 16 double-k-tiles

typedef __attribute__((ext_vector_type(8))) short bf16x8;
typedef __attribute__((ext_vector_type(4))) float f32x4;

// softmax scale folded into Q at QKV epilogue: 1/sqrt(64) * log2(e)
#define QSCALE 0.1803368801111244f
// defer-max threshold in log2 domain (= 8 nats)
#define THR_L2 11.541560327f

static __device__ __forceinline__ unsigned short f2bf(float f) {
  union { float f; unsigned u; } v; v.f = f;
  unsigned r = v.u + 0x7fffu + ((v.u >> 16) & 1u);
  return (unsigned short)(r >> 16);
}

static __device__ __forceinline__ float exp2_fast(float x) {
  float r;
  asm("v_exp_f32 %0, %1" : "=v"(r) : "v"(x));
  return r;
}

static __device__ __forceinline__ unsigned cvt_pk_bf16(float a, float b) {
  unsigned r;
  asm("v_cvt_pk_bf16_f32 %0, %1, %2" : "=v"(r) : "v"(a), "v"(b));
  return r;
}

// byte-offset swizzle: row-major LDS tile with 128B rows (16B granular XOR)
static __device__ __forceinline__ int swz128(int row, int g) {
  return ((row << 7) + (g << 4)) ^ ((row & 7) << 4);
}

// P-tile slot swizzle: 16 8B-slots per 128B row; bijective over 16 lanes
static __device__ __forceinline__ int xs4(int lr) {
  return ((lr & 7) << 1) | (lr >> 3);
}

static __device__ __forceinline__ void load_lds16(const void* g, void* l) {
  __builtin_amdgcn_global_load_lds(
      (const __attribute__((address_space(1))) unsigned*)g,
      (__attribute__((address_space(3))) unsigned*)l, 16, 0, 0);
}

// ---------------- converts ----------------

__global__ void cvt_bf16_kernel(const float* __restrict__ src,
                                unsigned short* __restrict__ dst, int n) {
  int i = (blockIdx.x * blockDim.x + threadIdx.x) * 8;
  if (i >= n) return;
  float4 v0 = *reinterpret_cast<const float4*>(src + i);
  float4 v1 = *reinterpret_cast<const float4*>(src + i + 4);
  ushort4 o0, o1;
  o0.x = f2bf(v0.x); o0.y = f2bf(v0.y); o0.z = f2bf(v0.z); o0.w = f2bf(v0.w);
  o1.x = f2bf(v1.x); o1.y = f2bf(v1.y); o1.z = f2bf(v1.z); o1.w = f2bf(v1.w);
  *reinterpret_cast<ushort4*>(dst + i) = o0;
  *reinterpret_cast<ushort4*>(dst + i + 4) = o1;
}

// W[i][o] fp32 -> Wt[o][i] bf16. z = 0..2: Wq/Wk/Wv into Wqkvt; z = 3: Wo.
__global__ void transpose_cvt_kernel(const float* __restrict__ Wq, const float* __restrict__ Wk,
                                     const float* __restrict__ Wv, const float* __restrict__ Wo,
                                     unsigned short* __restrict__ Wqkvt,
                                     unsigned short* __restrict__ Wot) {
  __shared__ float tile[32][33];
  int m = blockIdx.z;
  const float* src = (m == 0) ? Wq : (m == 1) ? Wk : (m == 2) ? Wv : Wo;
  unsigned short* dst = (m < 3) ? (Wqkvt + (size_t)m * D_MODEL * D_MODEL) : Wot;
  int i0 = blockIdx.y * 32, o0 = blockIdx.x * 32;
  int tx = threadIdx.x, ty = threadIdx.y;
  for (int k = 0; k < 32; k += 8)
    tile[ty + k][tx] = src[(size_t)(i0 + ty + k) * D_MODEL + o0 + tx];
  __syncthreads();
  for (int k = 0; k < 32; k += 8)
    dst[(size_t)(o0 + ty + k) * D_MODEL + i0 + tx] = f2bf(tile[tx][ty + k]);
}

// ---------------- QKV GEMM: 128x128 tile, BK=64, global_load_lds staging ----
// (unchanged from round 9 — verified race-free)

__global__ __launch_bounds__(256, 3) void gemm_qkv_kernel(
    const unsigned short* __restrict__ A, const unsigned short* __restrict__ Bt,
    const float* __restrict__ b0, const float* __restrict__ b1, const float* __restrict__ b2,
    unsigned short* __restrict__ Qb, unsigned short* __restrict__ Kb,
    unsigned short* __restrict__ Vtb)
{
  __shared__ char As[16384];   // 128 rows x 64 shorts (128B rows)
  __shared__ char Bs[16384];
  const int K = D_MODEL;
  // T1: XCD-chunked bijective block swizzle (768 % 8 == 0)
  int gx = gridDim.x;
  int orig = blockIdx.y * gx + blockIdx.x;
  int chunk = (gx * gridDim.y) >> 3;
  int sw = (orig & 7) * chunk + (orig >> 3);
  int m0 = (sw / gx) * 128, n0 = (sw % gx) * 128;
  int tid = threadIdx.x;
  int wv = tid >> 6, l = tid & 63;
  int wm = wv >> 1, wn = wv & 1;
  int lg = l >> 4, lr = l & 15;

  int sr = wv * 32 + (l >> 3);
  int csw = ((l & 7) ^ (l >> 3)) << 3;   // shorts
  const unsigned short* gaA = A  + (size_t)(m0 + sr) * K + csw;
  const unsigned short* gaB = Bt + (size_t)(n0 + sr) * K + csw;

  int gk0 = ((lg       ^ (lr & 7)) << 4);
  int gk1 = (((4 + lg) ^ (lr & 7)) << 4);
  int arow = (wm * 64 + lr) * 128;
  int brow = (wn * 64 + lr) * 128;

  f32x4 acc[4][4];
#pragma unroll
  for (int i = 0; i < 4; i++)
#pragma unroll
    for (int j = 0; j < 4; j++) acc[i][j] = (f32x4){0.f, 0.f, 0.f, 0.f};

  for (int k0 = 0; k0 < K; k0 += 64) {
    __syncthreads();
#pragma unroll
    for (int i = 0; i < 4; i++) {
      load_lds16(gaA + k0 + i * 8 * K, As + wv * 4096 + i * 1024);
      load_lds16(gaB + k0 + i * 8 * K, Bs + wv * 4096 + i * 1024);
    }
    __syncthreads();

    bf16x8 af0[4], af1[4], bf0[4], bf1[4];
#pragma unroll
    for (int mi = 0; mi < 4; mi++) {
      af0[mi] = *reinterpret_cast<const bf16x8*>(As + arow + mi * 2048 + gk0);
      af1[mi] = *reinterpret_cast<const bf16x8*>(As + arow + mi * 2048 + gk1);
    }
#pragma unroll
    for (int ni = 0; ni < 4; ni++) {
      bf0[ni] = *reinterpret_cast<const bf16x8*>(Bs + brow + ni * 2048 + gk0);
      bf1[ni] = *reinterpret_cast<const bf16x8*>(Bs + brow + ni * 2048 + gk1);
    }
#pragma unroll
    for (int mi = 0; mi < 4; mi++)
#pragma unroll
      for (int ni = 0; ni < 4; ni++) {
        acc[mi][ni] = __builtin_amdgcn_mfma_f32_16x16x32_bf16(af0[mi], bf0[ni], acc[mi][ni], 0, 0, 0);
        acc[mi][ni] = __builtin_amdgcn_mfma_f32_16x16x32_bf16(af1[mi], bf1[ni], acc[mi][ni], 0, 0, 0);
      }
  }

  if (n0 < 2048) {
    // ---- Q / K scalar epilogue ----
#pragma unroll
    for (int mi = 0; mi < 4; mi++) {
      int gr0 = m0 + wm * 64 + mi * 16 + lg * 4;
#pragma unroll
      for (int ni = 0; ni < 4; ni++) {
        int gc = n0 + wn * 64 + ni * 16 + lr;
        int mat = gc >> 10, o = gc & 1023;
        int hh = o >> 6, d = o & 63;
        float bv = (mat == 0) ? b0[o] : b1[o];
#pragma unroll
        for (int r = 0; r < 4; r++) {
          int t = gr0 + r;
          int b = t >> 11, s = t & 2047;
          float v = acc[mi][ni][r] + bv;
          if (mat == 0) v *= QSCALE;
          unsigned short u = f2bf(v);
          size_t head = (size_t)(b * HEADS + hh);
          if (mat == 0)
            Qb[(head * SEQ + s) * HSZ + d] = u;
          else                 // K pre-swizzled: element idx ^ ((s&7)<<3)
            Kb[((head * SEQ + s) * HSZ + d) ^ ((s & 7) << 3)] = u;
        }
      }
    }
  } else {
    // ---- V epilogue: single-pass LDS-bounce transpose ----
    int bglob = m0 >> 11;
    int hh0 = (n0 - 2048) >> 6;
    float bvv[4];
#pragma unroll
    for (int ni = 0; ni < 4; ni++) bvv[ni] = b2[(n0 - 2048) + wn * 64 + ni * 16 + lr];

    __syncthreads();   // all fragment ds_reads of the main loop done
    {
      char* dstbuf = (wm == 0) ? As : Bs;
#pragma unroll
      for (int mi = 0; mi < 4; mi++) {
        int lrow = mi * 16 + lg * 4;
#pragma unroll
        for (int ni = 0; ni < 4; ni++) {
          int cc = wn * 64 + ni * 16 + lr;
          uint2 pw;
          pw.x = cvt_pk_bf16(acc[mi][ni][0] + bvv[ni], acc[mi][ni][1] + bvv[ni]);
          pw.y = cvt_pk_bf16(acc[mi][ni][2] + bvv[ni], acc[mi][ni][3] + bvv[ni]);
          int ba = (cc * 128 + lrow * 2) ^ ((cc & 7) << 3);
          *reinterpret_cast<uint2*>(dstbuf + ba) = pw;
        }
      }
    }
    __syncthreads();
    int ck = tid & 7;
#pragma unroll
    for (int pass = 0; pass < 4; ++pass) {
      int cc = (tid >> 3) + pass * 32;
      int x = cc & 7;
      int d = cc & 63, hh = hh0 + (cc >> 6);
      size_t rowbase = (((size_t)(bglob * HEADS + hh)) * HSZ + d) * SEQ;
      int slo = ((ck * 2)     ^ x) << 3;
      int shi = ((ck * 2 + 1) ^ x) << 3;
      {
        uint2 lo = *reinterpret_cast<const uint2*>(As + (cc << 7) + slo);
        uint2 hi = *reinterpret_cast<const uint2*>(As + (cc << 7) + shi);
        int s = (m0 & 2047) + ck * 8;
        size_t idx = (rowbase + s) ^ ((d & 7) << 3);
        uint4 val = {lo.x, lo.y, hi.x, hi.y};
        *reinterpret_cast<uint4*>(Vtb + idx) = val;
      }
      {
        uint2 lo = *reinterpret_cast<const uint2*>(Bs + (cc << 7) + slo);
        uint2 hi = *reinterpret_cast<const uint2*>(Bs + (cc << 7) + shi);
        int s = (m0 & 2047) + 64 + ck * 8;
        size_t idx = (rowbase + s) ^ ((d & 7) << 3);
        uint4 val = {lo.x, lo.y, hi.x, hi.y};
        *reinterpret_cast<uint4*>(Vtb + idx) = val;
      }
    }
  }
}

// ---------------- proj GEMM: 128x128 tile, 512 threads (8 waves = 2M x 4N) ----

__global__ __launch_bounds__(512, 2) void gemm_proj_kernel(
    const unsigned short* __restrict__ A, const unsigned short* __restrict__ Bt,
    const float* __restrict__ bias, float* __restrict__ Cout)
{
  __shared__ char As[16384];   // 128 x 64 shorts
  __shared__ char Bs[16384];
  const int K = D_MODEL;
  int gx = gridDim.x;   // 8
  int orig = blockIdx.y * gx + blockIdx.x;
  int chunk = (gx * gridDim.y) >> 3;   // 32
  int sw = (orig & 7) * chunk + (orig >> 3);
  int m0 = (sw >> 3) * 128, n0 = (sw & 7) * 128;
  int tid = threadIdx.x;
  int wv = tid >> 6, l = tid & 63;
  int wm = wv >> 2, wn = wv & 3;       // 2M x 4N wave grid
  int lg = l >> 4, lr = l & 15;

  int srow = tid >> 3;                 // 0..63
  int csw = (((tid & 7) ^ (srow & 7)) << 3);
  const unsigned short* gaA = A  + (size_t)(m0 + srow) * K + csw;
  const unsigned short* gaB = Bt + (size_t)(n0 + srow) * K + csw;

  int gk0 = ((lg       ^ (lr & 7)) << 4);
  int gk1 = (((4 + lg) ^ (lr & 7)) << 4);
  int arow = (wm * 64 + lr) * 128;
  int brow = (wn * 32 + lr) * 128;

  f32x4 acc[4][2];
#pragma unroll
  for (int i = 0; i < 4; i++)
#pragma unroll
    for (int j = 0; j < 2; j++) acc[i][j] = (f32x4){0.f, 0.f, 0.f, 0.f};

  for (int k0 = 0; k0 < K; k0 += 64) {
    __syncthreads();
#pragma unroll
    for (int i = 0; i < 2; i++) {
      load_lds16(gaA + k0 + (size_t)i * 64 * K, As + i * 8192 + wv * 1024);
      load_lds16(gaB + k0 + (size_t)i * 64 * K, Bs + i * 8192 + wv * 1024);
    }
    __syncthreads();

    bf16x8 af0[4], af1[4], bf0[2], bf1[2];
#pragma unroll
    for (int mi = 0; mi < 4; mi++) {
      af0[mi] = *reinterpret_cast<const bf16x8*>(As + arow + mi * 2048 + gk0);
      af1[mi] = *reinterpret_cast<const bf16x8*>(As + arow + mi * 2048 + gk1);
    }
#pragma unroll
    for (int ni = 0; ni < 2; ni++) {
      bf0[ni] = *reinterpret_cast<const bf16x8*>(Bs + brow + ni * 2048 + gk0);
      bf1[ni] = *reinterpret_cast<const bf16x8*>(Bs + brow + ni * 2048 + gk1);
    }
#pragma unroll
    for (int mi = 0; mi < 4; mi++)
#pragma unroll
      for (int ni = 0; ni < 2; ni++) {
        acc[mi][ni] = __builtin_amdgcn_mfma_f32_16x16x32_bf16(af0[mi], bf0[ni], acc[mi][ni], 0, 0, 0);
        acc[mi][ni] = __builtin_amdgcn_mfma_f32_16x16x32_bf16(af1[mi], bf1[ni], acc[mi][ni], 0, 0, 0);
      }
  }

#pragma unroll
  for (int mi = 0; mi < 4; mi++) {
    int gr0 = m0 + wm * 64 + mi * 16 + lg * 4;
#pragma unroll
    for (int ni = 0; ni < 2; ni++) {
      int gc = n0 + wn * 32 + ni * 16 + lr;
      float bv = bias[gc];
#pragma unroll
      for (int r = 0; r < 4; r++)
        Cout[(size_t)(gr0 + r) * D_MODEL + gc] = acc[mi][ni][r] + bv;
    }
  }
}

// ---------------- flash attention: KVBLK=128, one barrier per 128 k-values ----
// Two 64-row mini-bodies (identical to the proven round-6 body) share one
// stage + one barrier. LDS 80KB x 2 blocks/CU = 160KB exactly.

#define KOFF(c) ((c) * 16384)
#define VOFF(c) (32768 + (c) * 16384)
#define POFF(w) (65536 + (w) * 2048)

__global__ __launch_bounds__(512, 4) void attn_kernel(
    const unsigned short* __restrict__ Qb, const unsigned short* __restrict__ Kb,
    const unsigned short* __restrict__ Vtb, unsigned short* __restrict__ Mg)
{
  __shared__ char lds[81920];   // K[2][16K] | V[2][16K] | P[8][2K]

  int orig = blockIdx.y * 16 + blockIdx.x;
  int swzb = (orig & 7) * 64 + (orig >> 3);
  int bh = swzb >> 4;
  int q0 = (swzb & 15) * 128;
  int b = bh >> 4, h = bh & 15;
  int tid = threadIdx.x, w = tid >> 6, l = tid & 63;
  int lg = l >> 4, lr = l & 15;
  const unsigned short* Qh = Qb + (size_t)bh * SEQ * HSZ;
  const char* Kg = (const char*)(Kb + (size_t)bh * SEQ * HSZ) + (size_t)tid * 16;
  const char* Vg = (const char*)(Vtb + (size_t)bh * HSZ * SEQ)
                   + (size_t)(tid >> 3) * (SEQ * 2) + (tid & 7) * 16;

  // hoisted LDS addresses: one base per k2 (swz128 XOR hits byte bit 6 — no "+64")
  int dsb[2] = { swz128(lr, lg), swz128(lr, lg + 4) };
  int pwa[4], paa[4];
#pragma unroll
  for (int ni = 0; ni < 4; ni++)
    pwa[ni] = POFF(w) + (lr << 7) + ((((ni << 2) + lg) ^ xs4(lr)) << 3);
#pragma unroll
  for (int k2 = 0; k2 < 2; k2++)
#pragma unroll
    for (int hh = 0; hh < 2; hh++)
      paa[k2 * 2 + hh] = POFF(w) + (lr << 7) + (((k2 * 8 + lg * 2 + hh) ^ xs4(lr)) << 3);

  bf16x8 qf2[2];
#pragma unroll
  for (int k2 = 0; k2 < 2; k2++)
    qf2[k2] = *reinterpret_cast<const bf16x8*>(
        Qh + (size_t)(q0 + w * 16 + lr) * HSZ + k2 * 32 + lg * 8);

  f32x4 of[4];
  f32x4 lones = (f32x4){0.f, 0.f, 0.f, 0.f};
#pragma unroll
  for (int ni = 0; ni < 4; ni++) of[ni] = (f32x4){0.f, 0.f, 0.f, 0.f};
  float m_r = -1e30f;

  bf16x8 vone;
#pragma unroll
  for (int j = 0; j < 8; j++) vone[j] = (short)0x3F80;   // bf16 1.0

  // stage one 128-k-tile (two 8KB sub-tiles each of K and V)
  auto stage = [&](int t, int nb) {
    if (t < NT2) {
      load_lds16(Kg + (size_t)t * 16384,        lds + KOFF(nb) + w * 1024);
      load_lds16(Kg + (size_t)t * 16384 + 8192, lds + KOFF(nb) + 8192 + w * 1024);
      load_lds16(Vg + (size_t)t * 256,          lds + VOFF(nb) + w * 1024);
      load_lds16(Vg + (size_t)t * 256 + 128,    lds + VOFF(nb) + 8192 + w * 1024);
    }
  };

  // one 64-row sub-tile: QK^T -> online softmax -> P -> PV
  auto mini = [&](int kbase, int vbase) {
    f32x4 sf[4];
#pragma unroll
    for (int ni = 0; ni < 4; ni++) {
      sf[ni] = (f32x4){0.f, 0.f, 0.f, 0.f};
#pragma unroll
      for (int k2 = 0; k2 < 2; k2++) {
        bf16x8 kf = *reinterpret_cast<const bf16x8*>(lds + dsb[k2] + kbase + ni * 2048);
        sf[ni] = __builtin_amdgcn_mfma_f32_16x16x32_bf16(kf, qf2[k2], sf[ni], 0, 0, 0);
      }
    }

    float lm = fmaxf(fmaxf(fmaxf(sf[0][0], sf[0][1]), fmaxf(sf[0][2], sf[0][3])),
                     fmaxf(fmaxf(sf[1][0], sf[1][1]), fmaxf(sf[1][2], sf[1][3])));
    lm = fmaxf(lm,
         fmaxf(fmaxf(fmaxf(sf[2][0], sf[2][1]), fmaxf(sf[2][2], sf[2][3])),
               fmaxf(fmaxf(sf[3][0], sf[3][1]), fmaxf(sf[3][2], sf[3][3]))));

    if (__any(lm > m_r + THR_L2)) {
      float vm = fmaxf(lm, __shfl_xor(lm, 16));
      vm = fmaxf(vm, __shfl_xor(vm, 32));
      float mn = fmaxf(m_r, vm);
      float al = exp2_fast(m_r - mn);
      m_r = mn;
#pragma unroll
      for (int r = 0; r < 4; r++) {
        float a = __shfl(al, lg * 4 + r, 16);
        lones[r] *= a;
#pragma unroll
        for (int ni = 0; ni < 4; ni++) of[ni][r] *= a;
      }
    }

#pragma unroll
    for (int ni = 0; ni < 4; ni++) {
      uint2 pw;
      pw.x = cvt_pk_bf16(exp2_fast(sf[ni][0] - m_r), exp2_fast(sf[ni][1] - m_r));
      pw.y = cvt_pk_bf16(exp2_fast(sf[ni][2] - m_r), exp2_fast(sf[ni][3] - m_r));
      *reinterpret_cast<uint2*>(lds + pwa[ni]) = pw;
    }

    bf16x8 pa[2];
#pragma unroll
    for (int k2 = 0; k2 < 2; k2++) {
      uint2 lo = *reinterpret_cast<const uint2*>(lds + paa[k2 * 2]);
      uint2 hi = *reinterpret_cast<const uint2*>(lds + paa[k2 * 2 + 1]);
      int4 tt = {(int)lo.x, (int)lo.y, (int)hi.x, (int)hi.y};
      pa[k2] = *reinterpret_cast<bf16x8*>(&tt);
    }

    __builtin_amdgcn_s_setprio(1);
#pragma unroll
    for (int k2 = 0; k2 < 2; k2++)
      lones = __builtin_amdgcn_mfma_f32_16x16x32_bf16(pa[k2], vone, lones, 0, 0, 0);
#pragma unroll
    for (int ni = 0; ni < 4; ni++)
#pragma unroll
      for (int k2 = 0; k2 < 2; k2++) {
        bf16x8 vf = *reinterpret_cast<const bf16x8*>(lds + dsb[k2] + vbase + ni * 2048);
        of[ni] = __builtin_amdgcn_mfma_f32_16x16x32_bf16(pa[k2], vf, of[ni], 0, 0, 0);
      }
    __builtin_amdgcn_s_setprio(0);
  };

  auto body = [&](int t, int cur) {
    stage(t + 1, cur ^ 1);                       // fire-and-forget into other buffer
    mini(KOFF(cur),        VOFF(cur));           // sub-tile 0 (k rows 0-63)
    mini(KOFF(cur) + 8192, VOFF(cur) + 8192);    // sub-tile 1 (k rows 64-127)
    __syncthreads();                             // ONE barrier per 128 k-values
  };

  stage(0, 0);
  __syncthreads();
  for (int kt = 0; kt < NT2; kt += 2) {
    body(kt, 0);
    body(kt + 1, 1);
  }

  // epilogue: merged[b][q][h*64+d], q = q0+w*16+lg*4+r, d = ni*16+lr
#pragma unroll
  for (int r = 0; r < 4; r++) {
    float inv = 1.0f / lones[r];
    int q = q0 + w * 16 + lg * 4 + r;
#pragma unroll
    for (int ni = 0; ni < 4; ni++) {
      int dm = h * 64 + ni * 16 + lr;
      Mg[(size_t)(b * SEQ + q) * D_MODEL + dm] = f2bf(of[ni][r] * inv);
    }
  }
}

// ---------------- launch ----------------

extern "C" void kernel_launch(void* const* d_in, const int* in_sizes, int n_in,
                              void* d_out, int out_size, void* d_ws, size_t ws_size,
                              hipStream_t stream) {
  const float* X  = (const float*)d_in[0];
  const float* Wq = (const float*)d_in[1];
  const float* bq = (const float*)d_in[2];
  const float* Wk = (const float*)d_in[3];
  const float* bk = (const float*)d_in[4];
  const float* Wv = (const float*)d_in[5];
  const float* bv = (const float*)d_in[6];
  const float* Wo = (const float*)d_in[7];
  const float* bo = (const float*)d_in[8];
  float* out = (float*)d_out;

  char* ws = (char*)d_ws;
  unsigned short* Xbf   = (unsigned short*)(ws);                      // 8 MB (reused as merged)
  unsigned short* Wqkvt = (unsigned short*)(ws + ((size_t)8  << 20)); // 6 MB
  unsigned short* Wot   = (unsigned short*)(ws + ((size_t)14 << 20)); // 2 MB
  unsigned short* Qb    = (unsigned short*)(ws + ((size_t)16 << 20)); // 8 MB
  unsigned short* Kb    = (unsigned short*)(ws + ((size_t)24 << 20)); // 8 MB
  unsigned short* Vtb   = (unsigned short*)(ws + ((size_t)32 << 20)); // 8 MB
  unsigned short* Mg = Xbf;  // Xbf dead after QKV GEMM

  cvt_bf16_kernel<<<(TOK * D_MODEL / 8 + 255) / 256, 256, 0, stream>>>(X, Xbf, TOK * D_MODEL);
  transpose_cvt_kernel<<<dim3(32, 32, 4), dim3(32, 8), 0, stream>>>(Wq, Wk, Wv, Wo, Wqkvt, Wot);
  gemm_qkv_kernel<<<dim3(24, 32), 256, 0, stream>>>(Xbf, Wqkvt, bq, bk, bv, Qb, Kb, Vtb);
  attn_kernel<<<dim3(16, 32), 512, 0, stream>>>(Qb, Kb, Vtb, Mg);
  gemm_proj_kernel<<<dim3(8, 32), 512, 0, stream>>>(Mg, Wot, bo, out);
}